// Round 13
// baseline (3949.242 us; speedup 1.0000x reference)
//
#include <hip/hip_runtime.h>

// CNF fused RK4, 3-chain bf16 MFMA (primal + 2 JVP tangents), ALL B-operands
// from the single c-scaled W2 LDS table (128 KB). 768 thr = 12 waves =
// 3 waves/SIMD (proven geometry). R13 = R9 + R10's numerically-proven pk-L1
// (v_pk_fma_f32 z-chain on paired l1a/l1b tables, scalar tanh). R12's
// tanh_pair / pk-epilogue / sleep-skew reverted (NaN, undiagnosed).

typedef __attribute__((ext_vector_type(8))) short bf16x8;
typedef __attribute__((ext_vector_type(8))) unsigned short u16x8;
typedef __attribute__((ext_vector_type(4))) float f32x4;
typedef __attribute__((ext_vector_type(4))) unsigned u32x4;
typedef __attribute__((ext_vector_type(2))) float f32x2;

#define CSC 2.8853900817779268f      /* 2*log2(e) */
#define INV_C2 0.12011325347010204f  /* 1/CSC^2 */

__device__ __forceinline__ unsigned short f2bf(float f) {
  unsigned u = __builtin_bit_cast(unsigned, f);
  u += 0x7FFFu + ((u >> 16) & 1u);   // RNE
  return (unsigned short)(u >> 16);
}

__device__ __forceinline__ unsigned pk2bf(float lo, float hi) {
  unsigned r;
  asm("v_cvt_pk_bf16_f32 %0, %1, %2" : "=v"(r) : "v"(lo), "v"(hi));
  return r;
}

// tanh from PRE-SCALED argument zs = 2*log2(e)*z : tanh(z) = 1 - 2/(2^zs + 1)
__device__ __forceinline__ float tanh_s(float zs) {
  float e;
  asm("v_exp_f32 %0, %1" : "=v"(e) : "v"(zs));
  return 1.0f - 2.0f * __builtin_amdgcn_rcpf(e + 1.0f);
}

__device__ __forceinline__ f32x2 pkfma(f32x2 a, f32x2 b, f32x2 c) {
  f32x2 d;
  asm("v_pk_fma_f32 %0, %1, %2, %3" : "=v"(d) : "v"(a), "v"(b), "v"(c));
  return d;
}

// ---------- prep: swizzle c*W2 -> bf16 B-fragment layout in d_ws ----------
// chunk c holds B[k=(c>>4)*32+(l>>4)*8+bb][j=(c&15)*16+(l&15)] at c*512+l*8+bb
__global__ void cnf_prep(const float* __restrict__ W2,
                         unsigned short* __restrict__ w2s) {
  int t = blockIdx.x * blockDim.x + threadIdx.x;   // 8192 threads
  if (t >= 8192) return;
  int c = t >> 6, l = t & 63;
  int kbase = ((c >> 4) << 5) + ((l >> 4) << 3);
  int j = ((c & 15) << 4) + (l & 15);
  int o = t * 8;
  #pragma unroll
  for (int bb = 0; bb < 8; ++bb)
    w2s[o + bb] = f2bf(CSC * W2[(kbase + bb) * 256 + j]);
}

// ---------- main fused RK4 kernel ----------
__launch_bounds__(768, 3)
__global__ void cnf_rk4_v13(const float* __restrict__ xg,
                            const float* __restrict__ W1,
                            const float* __restrict__ b1,
                            const float* __restrict__ W2f,
                            const float* __restrict__ b2,
                            const float* __restrict__ W3,
                            const float* __restrict__ b3,
                            const unsigned short* __restrict__ w2s,
                            const int* __restrict__ nsp,
                            float* __restrict__ out,
                            int Btot, int useWs) {
  __shared__ __align__(16) unsigned short w2u[65536];  // 128 KB, c*W2 B-frags
  __shared__ f32x4 l1a[128];    // {cW1_0[2i],cW1_0[2i+1],cW1_1[2i],cW1_1[2i+1]}
  __shared__ f32x4 l1b[128];    // {cW1_2[2i],cW1_2[2i+1],c*b1[2i],c*b1[2i+1]}
  __shared__ float4 eps[256];   // (W3_0, W3_1, c*b2, 0)
  __shared__ float  b3s[2];
  __shared__ float  cxs[192][2];
  __shared__ float  sxs[192][2];
  __shared__ float  ksum[192][2];
  __shared__ float  lsum[192];
  __shared__ float  lds_ld[192];

  const int tid  = threadIdx.x;
  const int lane = tid & 63;
  const int wv   = tid >> 6;       // wave 0..11
  const int ln15 = lane & 15;
  const int g    = lane >> 4;

  if (useWs) {            // fast staging: vector copy of pre-swizzled bf16
    u16x8* dst = (u16x8*)w2u;
    const u16x8* src = (const u16x8*)w2s;
    for (int i = tid; i < 8192; i += 768) dst[i] = src[i];
  } else {                // fallback: convert in-kernel
    for (int i = tid; i < 65536; i += 768) {
      int c = i >> 9, l = (i >> 3) & 63, bb = i & 7;
      int k = ((c >> 4) << 5) + ((l >> 4) << 3) + bb;
      int j = ((c & 15) << 4) + (l & 15);
      w2u[i] = f2bf(CSC * W2f[k * 256 + j]);
    }
  }
  for (int i = tid; i < 128; i += 768) {
    int k0 = 2 * i, k1 = k0 + 1;
    f32x4 a, b;
    a[0] = CSC * W1[k0];       a[1] = CSC * W1[k1];
    a[2] = CSC * W1[256 + k0]; a[3] = CSC * W1[256 + k1];
    b[0] = CSC * W1[512 + k0]; b[1] = CSC * W1[512 + k1];
    b[2] = CSC * b1[k0];       b[3] = CSC * b1[k1];
    l1a[i] = a; l1b[i] = b;
  }
  for (int i = tid; i < 256; i += 768)
    eps[i] = make_float4(W3[2 * i], W3[2 * i + 1], CSC * b2[i], 0.0f);
  if (tid == 0) { b3s[0] = b3[0]; b3s[1] = b3[1]; }

  const int base = blockIdx.x * 192;
  for (int i = tid; i < 192; i += 768) {
    if (base + i < Btot) {
      float2 v = ((const float2*)xg)[base + i];
      cxs[i][0] = v.x; cxs[i][1] = v.y;
      sxs[i][0] = v.x; sxs[i][1] = v.y;
    } else {
      cxs[i][0] = 0.f; cxs[i][1] = 0.f; sxs[i][0] = 0.f; sxs[i][1] = 0.f;
    }
    lds_ld[i] = 0.0f;
  }
  __syncthreads();

  int nst = nsp[0];
  if (nst < 1 || nst > 100000) {
    float fv = __builtin_bit_cast(float, nsp[0]);
    nst = (int)fv;
  }
  if (nst < 1) nst = 1;
  if (nst > 1000) nst = 1000;
  const int nsteps = nst - 1;
  const float hstep = (nsteps > 0) ? 1.0f / (float)nsteps : 0.0f;

  const bf16x8* w2v = (const bf16x8*)w2u;
  const int sA = wv * 16 + ln15;

  for (int step = 0; step < nsteps; ++step) {
    const float t0 = step * hstep;
    #pragma unroll 1
    for (int st = 0; st < 4; ++st) {
      const float tcur = t0 + ((st == 1 || st == 2) ? 0.5f * hstep
                                                    : (st == 3 ? hstep : 0.0f));
      f32x2 tcp; tcp[0] = tcur; tcp[1] = tcur;
      f32x2 x0p, x1p;
      x0p[0] = x0p[1] = sxs[sA][0];
      x1p[0] = x1p[1] = sxs[sA][1];

      // ---- layer 1 ONCE per stage (R10-proven pk form): 8 kt, 3 chains ----
      bf16x8 hfA[8], u0A[8], u1A[8];
      #pragma unroll
      for (int kt = 0; kt < 8; ++kt) {
        const int i2b = kt * 16 + g * 4;
        u32x4 hu, u0u, u1u;
        #pragma unroll
        for (int pp = 0; pp < 4; ++pp) {
          f32x4 A  = l1a[i2b + pp];
          f32x4 Bq = l1b[i2b + pp];
          f32x2 w0 = __builtin_shufflevector(A, A, 0, 1);
          f32x2 w1 = __builtin_shufflevector(A, A, 2, 3);
          f32x2 wt = __builtin_shufflevector(Bq, Bq, 0, 1);
          f32x2 wb = __builtin_shufflevector(Bq, Bq, 2, 3);
          f32x2 z  = pkfma(w0, x0p, pkfma(w1, x1p, pkfma(wt, tcp, wb)));
          float ha = tanh_s(z[0]);
          float hb = tanh_s(z[1]);
          float ta = fmaf(-ha, ha, 1.0f);
          float tb = fmaf(-hb, hb, 1.0f);
          hu[pp]  = pk2bf(ha, hb);
          u0u[pp] = pk2bf(ta * A[0], tb * A[1]);   // th * cW1_0
          u1u[pp] = pk2bf(ta * A[2], tb * A[3]);   // th * cW1_1
        }
        hfA[kt] = __builtin_bit_cast(bf16x8, hu);
        u0A[kt] = __builtin_bit_cast(bf16x8, u0u);
        u1A[kt] = __builtin_bit_cast(bf16x8, u1u);
      }

      float po0[4] = {0,0,0,0}, po1[4] = {0,0,0,0}, ptr_[4] = {0,0,0,0};

      #pragma unroll 1
      for (int ph = 0; ph < 8; ++ph) {           // N eighth: j in [ph*32, +32)
        f32x4 aP[2], aU0[2], aU1[2];
        #pragma unroll
        for (int ni = 0; ni < 2; ++ni) {
          aP[ni] = (f32x4)0.0f; aU0[ni] = (f32x4)0.0f; aU1[ni] = (f32x4)0.0f;
        }
        __builtin_amdgcn_s_setprio(1);           // favor MFMA-phase waves
        #pragma unroll
        for (int kt = 0; kt < 8; ++kt) {
          #pragma unroll
          for (int ni = 0; ni < 2; ++ni) {
            const int c = kt * 16 + ph * 2 + ni;
            bf16x8 bw = w2v[c * 64 + lane];      // 1 LDS read feeds 3 MFMAs
            aP[ni]  = __builtin_amdgcn_mfma_f32_16x16x32_bf16(hfA[kt], bw, aP[ni],  0, 0, 0);
            aU0[ni] = __builtin_amdgcn_mfma_f32_16x16x32_bf16(u0A[kt], bw, aU0[ni], 0, 0, 0);
            aU1[ni] = __builtin_amdgcn_mfma_f32_16x16x32_bf16(u1A[kt], bw, aU1[ni], 0, 0, 0);
          }
        }
        __builtin_amdgcn_s_setprio(0);
        // epilogue; C layout: col=lane&15 (j), row b (sample).
        // aP is c-scaled (c*W2): aP + c*b2 is the exp argument directly.
        #pragma unroll
        for (int ni = 0; ni < 2; ++ni) {
          const int j = (ph * 2 + ni) * 16 + ln15;
          const float4 e = eps[j];               // w30, w31, c*b2
          #pragma unroll
          for (int b = 0; b < 4; ++b) {
            float h2 = tanh_s(aP[ni][b] + e.z);
            float th2 = fmaf(-h2, h2, 1.0f);
            po0[b]  = fmaf(h2, e.x, po0[b]);
            po1[b]  = fmaf(h2, e.y, po1[b]);
            ptr_[b] = fmaf(th2, fmaf(aU0[ni][b], e.x, aU1[ni][b] * e.y), ptr_[b]);
          }
        }
      }

      // reduce over 16 j-lanes, RK4 state update
      #pragma unroll
      for (int b = 0; b < 4; ++b) {
        float r0 = po0[b], r1 = po1[b], r2 = ptr_[b];
        #pragma unroll
        for (int off = 8; off > 0; off >>= 1) {
          r0 += __shfl_xor(r0, off, 64);
          r1 += __shfl_xor(r1, off, 64);
          r2 += __shfl_xor(r2, off, 64);
        }
        if (ln15 == 0) {
          const int s = wv * 16 + g * 4 + b;
          const float dx0 = r0 + b3s[0];
          const float dx1 = r1 + b3s[1];
          const float trv = r2 * INV_C2;         // undo c^2 from u-chain & W2
          float k0, k1v, kl;
          if (st == 0) { k0 = dx0; k1v = dx1; kl = trv; }
          else {
            const float w = (st == 3) ? 1.0f : 2.0f;
            k0 = ksum[s][0] + w * dx0; k1v = ksum[s][1] + w * dx1; kl = lsum[s] + w * trv;
          }
          ksum[s][0] = k0; ksum[s][1] = k1v; lsum[s] = kl;
          if (st < 3) {
            const float a = (st == 2) ? hstep : 0.5f * hstep;
            sxs[s][0] = cxs[s][0] + a * dx0;
            sxs[s][1] = cxs[s][1] + a * dx1;
          } else {
            const float c6 = hstep * (1.0f / 6.0f);
            const float nx0 = cxs[s][0] + c6 * k0;
            const float nx1 = cxs[s][1] + c6 * k1v;
            cxs[s][0] = nx0; cxs[s][1] = nx1;
            sxs[s][0] = nx0; sxs[s][1] = nx1;
            lds_ld[s] -= 0.01f * c6 * kl;        // -TRACE_SCALE * (h/6) * sum
          }
        }
      }
    }
  }
  __syncthreads();

  for (int i = tid; i < 192; i += 768) {
    const int gs = base + i;
    if (gs < Btot) {
      ((float2*)out)[gs] = make_float2(cxs[i][0], cxs[i][1]);
      out[2 * Btot + gs] = lds_ld[i];
    }
  }
}

extern "C" void kernel_launch(void* const* d_in, const int* in_sizes, int n_in,
                              void* d_out, int out_size, void* d_ws, size_t ws_size,
                              hipStream_t stream) {
  const float* x  = (const float*)d_in[0];
  const float* W1 = (const float*)d_in[1];
  const float* b1 = (const float*)d_in[2];
  const float* W2 = (const float*)d_in[3];
  const float* b2 = (const float*)d_in[4];
  const float* W3 = (const float*)d_in[5];
  const float* b3 = (const float*)d_in[6];
  const int* nsp  = (const int*)d_in[7];
  float* out = (float*)d_out;

  const int Btot = in_sizes[0] / 2;
  const int nblocks = (Btot + 191) / 192;

  const int useWs = (ws_size >= 65536u * sizeof(unsigned short)) ? 1 : 0;
  unsigned short* w2s = (unsigned short*)d_ws;
  if (useWs)
    cnf_prep<<<dim3(32), dim3(256), 0, stream>>>(W2, w2s);
  cnf_rk4_v13<<<dim3(nblocks), dim3(768), 0, stream>>>(
      x, W1, b1, W2, b2, W3, b3, w2s, nsp, out, Btot, useWs);
}

// Round 14
// 3896.111 us; speedup vs baseline: 1.0136x; 1.0136x over previous
//
#include <hip/hip_runtime.h>

// CNF fused RK4, 3-chain bf16 MFMA (primal + 2 JVP tangents), ALL B-operands
// from the single c-scaled W2 LDS table (128 KB). 768 thr = 12 waves =
// 3 waves/SIMD. R14 = R9 (proven 3.877 ms) + ONE change: one-time s_sleep
// wave skew so the 3 co-resident waves per SIMD run ~1/3-stage out of phase
// (VALU-phase of one wave overlaps MFMA/LDS-phase of another). No math change.

typedef __attribute__((ext_vector_type(8))) short bf16x8;
typedef __attribute__((ext_vector_type(8))) unsigned short u16x8;
typedef __attribute__((ext_vector_type(4))) float f32x4;
typedef __attribute__((ext_vector_type(4))) unsigned u32x4;

#define CSC 2.8853900817779268f      /* 2*log2(e) */
#define INV_C2 0.12011325347010204f  /* 1/CSC^2 */

__device__ __forceinline__ unsigned short f2bf(float f) {
  unsigned u = __builtin_bit_cast(unsigned, f);
  u += 0x7FFFu + ((u >> 16) & 1u);   // RNE
  return (unsigned short)(u >> 16);
}

__device__ __forceinline__ unsigned pk2bf(float lo, float hi) {
  unsigned r;
  asm("v_cvt_pk_bf16_f32 %0, %1, %2" : "=v"(r) : "v"(lo), "v"(hi));
  return r;
}

// tanh from PRE-SCALED argument zs = 2*log2(e)*z : tanh(z) = 1 - 2/(2^zs + 1)
__device__ __forceinline__ float tanh_s(float zs) {
  float e;
  asm("v_exp_f32 %0, %1" : "=v"(e) : "v"(zs));
  return 1.0f - 2.0f * __builtin_amdgcn_rcpf(e + 1.0f);
}

// ---------- prep: swizzle c*W2 -> bf16 B-fragment layout in d_ws ----------
// chunk c holds B[k=(c>>4)*32+(l>>4)*8+bb][j=(c&15)*16+(l&15)] at c*512+l*8+bb
__global__ void cnf_prep(const float* __restrict__ W2,
                         unsigned short* __restrict__ w2s) {
  int t = blockIdx.x * blockDim.x + threadIdx.x;   // 8192 threads
  if (t >= 8192) return;
  int c = t >> 6, l = t & 63;
  int kbase = ((c >> 4) << 5) + ((l >> 4) << 3);
  int j = ((c & 15) << 4) + (l & 15);
  int o = t * 8;
  #pragma unroll
  for (int bb = 0; bb < 8; ++bb)
    w2s[o + bb] = f2bf(CSC * W2[(kbase + bb) * 256 + j]);
}

// ---------- main fused RK4 kernel ----------
__launch_bounds__(768, 3)
__global__ void cnf_rk4_v14(const float* __restrict__ xg,
                            const float* __restrict__ W1,
                            const float* __restrict__ b1,
                            const float* __restrict__ W2f,
                            const float* __restrict__ b2,
                            const float* __restrict__ W3,
                            const float* __restrict__ b3,
                            const unsigned short* __restrict__ w2s,
                            const int* __restrict__ nsp,
                            float* __restrict__ out,
                            int Btot, int useWs) {
  __shared__ __align__(16) unsigned short w2u[65536];  // 128 KB, c*W2 B-frags
  __shared__ float4 l1c[288];   // c*(W1_0,W1_1,W1_2,b1) at k + (k>>3)
  __shared__ float4 eps[256];   // (W3_0, W3_1, c*b2, 0)
  __shared__ float  b3s[2];
  __shared__ float  cxs[192][2];
  __shared__ float  sxs[192][2];
  __shared__ float  ksum[192][2];
  __shared__ float  lsum[192];
  __shared__ float  lds_ld[192];

  const int tid  = threadIdx.x;
  const int lane = tid & 63;
  const int wv   = tid >> 6;       // wave 0..11
  const int ln15 = lane & 15;
  const int g    = lane >> 4;

  if (useWs) {            // fast staging: vector copy of pre-swizzled bf16
    u16x8* dst = (u16x8*)w2u;
    const u16x8* src = (const u16x8*)w2s;
    for (int i = tid; i < 8192; i += 768) dst[i] = src[i];
  } else {                // fallback: convert in-kernel
    for (int i = tid; i < 65536; i += 768) {
      int c = i >> 9, l = (i >> 3) & 63, bb = i & 7;
      int k = ((c >> 4) << 5) + ((l >> 4) << 3) + bb;
      int j = ((c & 15) << 4) + (l & 15);
      w2u[i] = f2bf(CSC * W2f[k * 256 + j]);
    }
  }
  for (int i = tid; i < 256; i += 768) {
    l1c[i + (i >> 3)] = make_float4(CSC * W1[i], CSC * W1[256 + i],
                                    CSC * W1[512 + i], CSC * b1[i]);
    eps[i] = make_float4(W3[2 * i], W3[2 * i + 1], CSC * b2[i], 0.0f);
  }
  if (tid == 0) { b3s[0] = b3[0]; b3s[1] = b3[1]; }

  const int base = blockIdx.x * 192;
  for (int i = tid; i < 192; i += 768) {
    if (base + i < Btot) {
      float2 v = ((const float2*)xg)[base + i];
      cxs[i][0] = v.x; cxs[i][1] = v.y;
      sxs[i][0] = v.x; sxs[i][1] = v.y;
    } else {
      cxs[i][0] = 0.f; cxs[i][1] = 0.f; sxs[i][0] = 0.f; sxs[i][1] = 0.f;
    }
    lds_ld[i] = 0.0f;
  }
  __syncthreads();

  // ---- one-time wave skew: waves {0-3},{4-7},{8-11} offset by ~15K cyc ----
  // (wave i maps to SIMD i%4, so wv>>2 indexes the co-resident cohort).
  // No barrier in the main loop -> skew persists; math is untouched.
  for (int i = (wv >> 2) * 15; i > 0; --i) __builtin_amdgcn_s_sleep(16);

  int nst = nsp[0];
  if (nst < 1 || nst > 100000) {
    float fv = __builtin_bit_cast(float, nsp[0]);
    nst = (int)fv;
  }
  if (nst < 1) nst = 1;
  if (nst > 1000) nst = 1000;
  const int nsteps = nst - 1;
  const float hstep = (nsteps > 0) ? 1.0f / (float)nsteps : 0.0f;

  const bf16x8* w2v = (const bf16x8*)w2u;
  const int sA = wv * 16 + ln15;

  for (int step = 0; step < nsteps; ++step) {
    const float t0 = step * hstep;
    #pragma unroll 1
    for (int st = 0; st < 4; ++st) {
      const float tcur = t0 + ((st == 1 || st == 2) ? 0.5f * hstep
                                                    : (st == 3 ? hstep : 0.0f));
      const float x0 = sxs[sA][0];
      const float x1 = sxs[sA][1];

      // ---- layer 1 ONCE per stage: A-frags for all 8 kt, 3 chains ----
      bf16x8 hfA[8], u0A[8], u1A[8];
      #pragma unroll
      for (int kt = 0; kt < 8; ++kt) {
        const int kb = kt * 32 + g * 8 + (kt * 4 + g);   // k + (k>>3) swizzle
        u32x4 hu, u0u, u1u;
        #pragma unroll
        for (int pp = 0; pp < 4; ++pp) {
          float4 qa = l1c[kb + 2 * pp];
          float4 qb = l1c[kb + 2 * pp + 1];
          float za = fmaf(x0, qa.x, fmaf(x1, qa.y, fmaf(tcur, qa.z, qa.w)));
          float zb = fmaf(x0, qb.x, fmaf(x1, qb.y, fmaf(tcur, qb.z, qb.w)));
          float ha = tanh_s(za);
          float hb = tanh_s(zb);
          float ta = fmaf(-ha, ha, 1.0f);
          float tb = fmaf(-hb, hb, 1.0f);
          hu[pp]  = pk2bf(ha, hb);
          u0u[pp] = pk2bf(ta * qa.x, tb * qb.x);   // th * (c*W1[0,k])
          u1u[pp] = pk2bf(ta * qa.y, tb * qb.y);   // th * (c*W1[1,k])
        }
        hfA[kt] = __builtin_bit_cast(bf16x8, hu);
        u0A[kt] = __builtin_bit_cast(bf16x8, u0u);
        u1A[kt] = __builtin_bit_cast(bf16x8, u1u);
      }

      float po0[4] = {0,0,0,0}, po1[4] = {0,0,0,0}, ptr_[4] = {0,0,0,0};

      #pragma unroll 1
      for (int ph = 0; ph < 8; ++ph) {           // N eighth: j in [ph*32, +32)
        f32x4 aP[2], aU0[2], aU1[2];
        #pragma unroll
        for (int ni = 0; ni < 2; ++ni) {
          aP[ni] = (f32x4)0.0f; aU0[ni] = (f32x4)0.0f; aU1[ni] = (f32x4)0.0f;
        }
        __builtin_amdgcn_s_setprio(1);           // favor MFMA-phase waves
        #pragma unroll
        for (int kt = 0; kt < 8; ++kt) {
          #pragma unroll
          for (int ni = 0; ni < 2; ++ni) {
            const int c = kt * 16 + ph * 2 + ni;
            bf16x8 bw = w2v[c * 64 + lane];      // 1 LDS read feeds 3 MFMAs
            aP[ni]  = __builtin_amdgcn_mfma_f32_16x16x32_bf16(hfA[kt], bw, aP[ni],  0, 0, 0);
            aU0[ni] = __builtin_amdgcn_mfma_f32_16x16x32_bf16(u0A[kt], bw, aU0[ni], 0, 0, 0);
            aU1[ni] = __builtin_amdgcn_mfma_f32_16x16x32_bf16(u1A[kt], bw, aU1[ni], 0, 0, 0);
          }
        }
        __builtin_amdgcn_s_setprio(0);
        // epilogue; C layout: col=lane&15 (j), row b (sample).
        // aP is c-scaled (c*W2): aP + c*b2 is the exp argument directly.
        #pragma unroll
        for (int ni = 0; ni < 2; ++ni) {
          const int j = (ph * 2 + ni) * 16 + ln15;
          const float4 e = eps[j];               // w30, w31, c*b2
          #pragma unroll
          for (int b = 0; b < 4; ++b) {
            float h2 = tanh_s(aP[ni][b] + e.z);
            float th2 = fmaf(-h2, h2, 1.0f);
            po0[b]  = fmaf(h2, e.x, po0[b]);
            po1[b]  = fmaf(h2, e.y, po1[b]);
            ptr_[b] = fmaf(th2, fmaf(aU0[ni][b], e.x, aU1[ni][b] * e.y), ptr_[b]);
          }
        }
      }

      // reduce over 16 j-lanes, RK4 state update
      #pragma unroll
      for (int b = 0; b < 4; ++b) {
        float r0 = po0[b], r1 = po1[b], r2 = ptr_[b];
        #pragma unroll
        for (int off = 8; off > 0; off >>= 1) {
          r0 += __shfl_xor(r0, off, 64);
          r1 += __shfl_xor(r1, off, 64);
          r2 += __shfl_xor(r2, off, 64);
        }
        if (ln15 == 0) {
          const int s = wv * 16 + g * 4 + b;
          const float dx0 = r0 + b3s[0];
          const float dx1 = r1 + b3s[1];
          const float trv = r2 * INV_C2;         // undo c^2 from u-chain & W2
          float k0, k1v, kl;
          if (st == 0) { k0 = dx0; k1v = dx1; kl = trv; }
          else {
            const float w = (st == 3) ? 1.0f : 2.0f;
            k0 = ksum[s][0] + w * dx0; k1v = ksum[s][1] + w * dx1; kl = lsum[s] + w * trv;
          }
          ksum[s][0] = k0; ksum[s][1] = k1v; lsum[s] = kl;
          if (st < 3) {
            const float a = (st == 2) ? hstep : 0.5f * hstep;
            sxs[s][0] = cxs[s][0] + a * dx0;
            sxs[s][1] = cxs[s][1] + a * dx1;
          } else {
            const float c6 = hstep * (1.0f / 6.0f);
            const float nx0 = cxs[s][0] + c6 * k0;
            const float nx1 = cxs[s][1] + c6 * k1v;
            cxs[s][0] = nx0; cxs[s][1] = nx1;
            sxs[s][0] = nx0; sxs[s][1] = nx1;
            lds_ld[s] -= 0.01f * c6 * kl;        // -TRACE_SCALE * (h/6) * sum
          }
        }
      }
    }
  }
  __syncthreads();

  for (int i = tid; i < 192; i += 768) {
    const int gs = base + i;
    if (gs < Btot) {
      ((float2*)out)[gs] = make_float2(cxs[i][0], cxs[i][1]);
      out[2 * Btot + gs] = lds_ld[i];
    }
  }
}

extern "C" void kernel_launch(void* const* d_in, const int* in_sizes, int n_in,
                              void* d_out, int out_size, void* d_ws, size_t ws_size,
                              hipStream_t stream) {
  const float* x  = (const float*)d_in[0];
  const float* W1 = (const float*)d_in[1];
  const float* b1 = (const float*)d_in[2];
  const float* W2 = (const float*)d_in[3];
  const float* b2 = (const float*)d_in[4];
  const float* W3 = (const float*)d_in[5];
  const float* b3 = (const float*)d_in[6];
  const int* nsp  = (const int*)d_in[7];
  float* out = (float*)d_out;

  const int Btot = in_sizes[0] / 2;
  const int nblocks = (Btot + 191) / 192;

  const int useWs = (ws_size >= 65536u * sizeof(unsigned short)) ? 1 : 0;
  unsigned short* w2s = (unsigned short*)d_ws;
  if (useWs)
    cnf_prep<<<dim3(32), dim3(256), 0, stream>>>(W2, w2s);
  cnf_rk4_v14<<<dim3(nblocks), dim3(768), 0, stream>>>(
      x, W1, b1, W2, b2, W3, b3, w2s, nsp, out, Btot, useWs);
}

// Round 16
// 3883.261 us; speedup vs baseline: 1.0170x; 1.0033x over previous
//
#include <hip/hip_runtime.h>

// CNF fused RK4, 3-chain bf16 MFMA (primal + 2 JVP tangents), ALL B-operands
// from the single c-scaled W2 LDS table (128 KB). 768 thr = 12 waves =
// 3 waves/SIMD. R16 = R9 (proven 3.877 ms / absmax 0.03125) + ONE change:
// kt=0 MFMAs take a shared never-written zero4 as C (bit-identical to zero
// init) -> deletes ~192 accumulator-init insts per wave-stage.
// R15's sigmoid-form reverted (absolute-error bf16 rounding of v, 4x worse
// conditioning -> absmax 1.38).

typedef __attribute__((ext_vector_type(8))) short bf16x8;
typedef __attribute__((ext_vector_type(8))) unsigned short u16x8;
typedef __attribute__((ext_vector_type(4))) float f32x4;
typedef __attribute__((ext_vector_type(4))) unsigned u32x4;

#define CSC 2.8853900817779268f      /* 2*log2(e) */
#define INV_C2 0.12011325347010204f  /* 1/CSC^2 */

__device__ __forceinline__ unsigned short f2bf(float f) {
  unsigned u = __builtin_bit_cast(unsigned, f);
  u += 0x7FFFu + ((u >> 16) & 1u);   // RNE
  return (unsigned short)(u >> 16);
}

__device__ __forceinline__ unsigned pk2bf(float lo, float hi) {
  unsigned r;
  asm("v_cvt_pk_bf16_f32 %0, %1, %2" : "=v"(r) : "v"(lo), "v"(hi));
  return r;
}

// tanh from PRE-SCALED argument zs = 2*log2(e)*z : tanh(z) = 1 - 2/(2^zs + 1)
__device__ __forceinline__ float tanh_s(float zs) {
  float e;
  asm("v_exp_f32 %0, %1" : "=v"(e) : "v"(zs));
  return 1.0f - 2.0f * __builtin_amdgcn_rcpf(e + 1.0f);
}

// ---------- prep: swizzle c*W2 -> bf16 B-fragment layout in d_ws ----------
// chunk c holds B[k=(c>>4)*32+(l>>4)*8+bb][j=(c&15)*16+(l&15)] at c*512+l*8+bb
__global__ void cnf_prep(const float* __restrict__ W2,
                         unsigned short* __restrict__ w2s) {
  int t = blockIdx.x * blockDim.x + threadIdx.x;   // 8192 threads
  if (t >= 8192) return;
  int c = t >> 6, l = t & 63;
  int kbase = ((c >> 4) << 5) + ((l >> 4) << 3);
  int j = ((c & 15) << 4) + (l & 15);
  int o = t * 8;
  #pragma unroll
  for (int bb = 0; bb < 8; ++bb)
    w2s[o + bb] = f2bf(CSC * W2[(kbase + bb) * 256 + j]);
}

// ---------- main fused RK4 kernel ----------
__launch_bounds__(768, 3)
__global__ void cnf_rk4_v16(const float* __restrict__ xg,
                            const float* __restrict__ W1,
                            const float* __restrict__ b1,
                            const float* __restrict__ W2f,
                            const float* __restrict__ b2,
                            const float* __restrict__ W3,
                            const float* __restrict__ b3,
                            const unsigned short* __restrict__ w2s,
                            const int* __restrict__ nsp,
                            float* __restrict__ out,
                            int Btot, int useWs) {
  __shared__ __align__(16) unsigned short w2u[65536];  // 128 KB, c*W2 B-frags
  __shared__ float4 l1c[288];   // c*(W1_0,W1_1,W1_2,b1) at k + (k>>3)
  __shared__ float4 eps[256];   // (W3_0, W3_1, c*b2, 0)
  __shared__ float  b3s[2];
  __shared__ float  cxs[192][2];
  __shared__ float  sxs[192][2];
  __shared__ float  ksum[192][2];
  __shared__ float  lsum[192];
  __shared__ float  lds_ld[192];

  const int tid  = threadIdx.x;
  const int lane = tid & 63;
  const int wv   = tid >> 6;       // wave 0..11
  const int ln15 = lane & 15;
  const int g    = lane >> 4;

  if (useWs) {            // fast staging: vector copy of pre-swizzled bf16
    u16x8* dst = (u16x8*)w2u;
    const u16x8* src = (const u16x8*)w2s;
    for (int i = tid; i < 8192; i += 768) dst[i] = src[i];
  } else {                // fallback: convert in-kernel
    for (int i = tid; i < 65536; i += 768) {
      int c = i >> 9, l = (i >> 3) & 63, bb = i & 7;
      int k = ((c >> 4) << 5) + ((l >> 4) << 3) + bb;
      int j = ((c & 15) << 4) + (l & 15);
      w2u[i] = f2bf(CSC * W2f[k * 256 + j]);
    }
  }
  for (int i = tid; i < 256; i += 768) {
    l1c[i + (i >> 3)] = make_float4(CSC * W1[i], CSC * W1[256 + i],
                                    CSC * W1[512 + i], CSC * b1[i]);
    eps[i] = make_float4(W3[2 * i], W3[2 * i + 1], CSC * b2[i], 0.0f);
  }
  if (tid == 0) { b3s[0] = b3[0]; b3s[1] = b3[1]; }

  const int base = blockIdx.x * 192;
  for (int i = tid; i < 192; i += 768) {
    if (base + i < Btot) {
      float2 v = ((const float2*)xg)[base + i];
      cxs[i][0] = v.x; cxs[i][1] = v.y;
      sxs[i][0] = v.x; sxs[i][1] = v.y;
    } else {
      cxs[i][0] = 0.f; cxs[i][1] = 0.f; sxs[i][0] = 0.f; sxs[i][1] = 0.f;
    }
    lds_ld[i] = 0.0f;
  }
  __syncthreads();

  int nst = nsp[0];
  if (nst < 1 || nst > 100000) {
    float fv = __builtin_bit_cast(float, nsp[0]);
    nst = (int)fv;
  }
  if (nst < 1) nst = 1;
  if (nst > 1000) nst = 1000;
  const int nsteps = nst - 1;
  const float hstep = (nsteps > 0) ? 1.0f / (float)nsteps : 0.0f;

  const bf16x8* w2v = (const bf16x8*)w2u;
  const int sA = wv * 16 + ln15;
  const f32x4 zero4 = {0.0f, 0.0f, 0.0f, 0.0f};   // shared C for peeled MFMAs

  for (int step = 0; step < nsteps; ++step) {
    const float t0 = step * hstep;
    #pragma unroll 1
    for (int st = 0; st < 4; ++st) {
      const float tcur = t0 + ((st == 1 || st == 2) ? 0.5f * hstep
                                                    : (st == 3 ? hstep : 0.0f));
      const float x0 = sxs[sA][0];
      const float x1 = sxs[sA][1];

      // ---- layer 1 ONCE per stage: A-frags for all 8 kt, 3 chains ----
      bf16x8 hfA[8], u0A[8], u1A[8];
      #pragma unroll
      for (int kt = 0; kt < 8; ++kt) {
        const int kb = kt * 32 + g * 8 + (kt * 4 + g);   // k + (k>>3) swizzle
        u32x4 hu, u0u, u1u;
        #pragma unroll
        for (int pp = 0; pp < 4; ++pp) {
          float4 qa = l1c[kb + 2 * pp];
          float4 qb = l1c[kb + 2 * pp + 1];
          float za = fmaf(x0, qa.x, fmaf(x1, qa.y, fmaf(tcur, qa.z, qa.w)));
          float zb = fmaf(x0, qb.x, fmaf(x1, qb.y, fmaf(tcur, qb.z, qb.w)));
          float ha = tanh_s(za);
          float hb = tanh_s(zb);
          float ta = fmaf(-ha, ha, 1.0f);
          float tb = fmaf(-hb, hb, 1.0f);
          hu[pp]  = pk2bf(ha, hb);
          u0u[pp] = pk2bf(ta * qa.x, tb * qb.x);   // th * (c*W1[0,k])
          u1u[pp] = pk2bf(ta * qa.y, tb * qb.y);   // th * (c*W1[1,k])
        }
        hfA[kt] = __builtin_bit_cast(bf16x8, hu);
        u0A[kt] = __builtin_bit_cast(bf16x8, u0u);
        u1A[kt] = __builtin_bit_cast(bf16x8, u1u);
      }

      float po0[4] = {0,0,0,0}, po1[4] = {0,0,0,0}, ptr_[4] = {0,0,0,0};

      #pragma unroll 1
      for (int ph = 0; ph < 8; ++ph) {           // N eighth: j in [ph*32, +32)
        f32x4 aP[2], aU0[2], aU1[2];
        __builtin_amdgcn_s_setprio(1);           // favor MFMA-phase waves
        #pragma unroll
        for (int ni = 0; ni < 2; ++ni) {         // kt = 0 peeled: C = zero4
          bf16x8 bw = w2v[(ph * 2 + ni) * 64 + lane];
          aP[ni]  = __builtin_amdgcn_mfma_f32_16x16x32_bf16(hfA[0], bw, zero4, 0, 0, 0);
          aU0[ni] = __builtin_amdgcn_mfma_f32_16x16x32_bf16(u0A[0], bw, zero4, 0, 0, 0);
          aU1[ni] = __builtin_amdgcn_mfma_f32_16x16x32_bf16(u1A[0], bw, zero4, 0, 0, 0);
        }
        #pragma unroll
        for (int kt = 1; kt < 8; ++kt) {
          #pragma unroll
          for (int ni = 0; ni < 2; ++ni) {
            const int c = kt * 16 + ph * 2 + ni;
            bf16x8 bw = w2v[c * 64 + lane];      // 1 LDS read feeds 3 MFMAs
            aP[ni]  = __builtin_amdgcn_mfma_f32_16x16x32_bf16(hfA[kt], bw, aP[ni],  0, 0, 0);
            aU0[ni] = __builtin_amdgcn_mfma_f32_16x16x32_bf16(u0A[kt], bw, aU0[ni], 0, 0, 0);
            aU1[ni] = __builtin_amdgcn_mfma_f32_16x16x32_bf16(u1A[kt], bw, aU1[ni], 0, 0, 0);
          }
        }
        __builtin_amdgcn_s_setprio(0);
        // epilogue; C layout: col=lane&15 (j), row b (sample).
        // aP is c-scaled (c*W2): aP + c*b2 is the exp argument directly.
        #pragma unroll
        for (int ni = 0; ni < 2; ++ni) {
          const int j = (ph * 2 + ni) * 16 + ln15;
          const float4 e = eps[j];               // w30, w31, c*b2
          #pragma unroll
          for (int b = 0; b < 4; ++b) {
            float h2 = tanh_s(aP[ni][b] + e.z);
            float th2 = fmaf(-h2, h2, 1.0f);
            po0[b]  = fmaf(h2, e.x, po0[b]);
            po1[b]  = fmaf(h2, e.y, po1[b]);
            ptr_[b] = fmaf(th2, fmaf(aU0[ni][b], e.x, aU1[ni][b] * e.y), ptr_[b]);
          }
        }
      }

      // reduce over 16 j-lanes, RK4 state update
      #pragma unroll
      for (int b = 0; b < 4; ++b) {
        float r0 = po0[b], r1 = po1[b], r2 = ptr_[b];
        #pragma unroll
        for (int off = 8; off > 0; off >>= 1) {
          r0 += __shfl_xor(r0, off, 64);
          r1 += __shfl_xor(r1, off, 64);
          r2 += __shfl_xor(r2, off, 64);
        }
        if (ln15 == 0) {
          const int s = wv * 16 + g * 4 + b;
          const float dx0 = r0 + b3s[0];
          const float dx1 = r1 + b3s[1];
          const float trv = r2 * INV_C2;         // undo c^2 from u-chain & W2
          float k0, k1v, kl;
          if (st == 0) { k0 = dx0; k1v = dx1; kl = trv; }
          else {
            const float w = (st == 3) ? 1.0f : 2.0f;
            k0 = ksum[s][0] + w * dx0; k1v = ksum[s][1] + w * dx1; kl = lsum[s] + w * trv;
          }
          ksum[s][0] = k0; ksum[s][1] = k1v; lsum[s] = kl;
          if (st < 3) {
            const float a = (st == 2) ? hstep : 0.5f * hstep;
            sxs[s][0] = cxs[s][0] + a * dx0;
            sxs[s][1] = cxs[s][1] + a * dx1;
          } else {
            const float c6 = hstep * (1.0f / 6.0f);
            const float nx0 = cxs[s][0] + c6 * k0;
            const float nx1 = cxs[s][1] + c6 * k1v;
            cxs[s][0] = nx0; cxs[s][1] = nx1;
            sxs[s][0] = nx0; sxs[s][1] = nx1;
            lds_ld[s] -= 0.01f * c6 * kl;        // -TRACE_SCALE * (h/6) * sum
          }
        }
      }
    }
  }
  __syncthreads();

  for (int i = tid; i < 192; i += 768) {
    const int gs = base + i;
    if (gs < Btot) {
      ((float2*)out)[gs] = make_float2(cxs[i][0], cxs[i][1]);
      out[2 * Btot + gs] = lds_ld[i];
    }
  }
}

extern "C" void kernel_launch(void* const* d_in, const int* in_sizes, int n_in,
                              void* d_out, int out_size, void* d_ws, size_t ws_size,
                              hipStream_t stream) {
  const float* x  = (const float*)d_in[0];
  const float* W1 = (const float*)d_in[1];
  const float* b1 = (const float*)d_in[2];
  const float* W2 = (const float*)d_in[3];
  const float* b2 = (const float*)d_in[4];
  const float* W3 = (const float*)d_in[5];
  const float* b3 = (const float*)d_in[6];
  const int* nsp  = (const int*)d_in[7];
  float* out = (float*)d_out;

  const int Btot = in_sizes[0] / 2;
  const int nblocks = (Btot + 191) / 192;

  const int useWs = (ws_size >= 65536u * sizeof(unsigned short)) ? 1 : 0;
  unsigned short* w2s = (unsigned short*)d_ws;
  if (useWs)
    cnf_prep<<<dim3(32), dim3(256), 0, stream>>>(W2, w2s);
  cnf_rk4_v16<<<dim3(nblocks), dim3(768), 0, stream>>>(
      x, W1, b1, W2, b2, W3, b3, w2s, nsp, out, Btot, useWs);
}